// Round 3
// baseline (331.820 us; speedup 1.0000x reference)
//
#include <hip/hip_runtime.h>
#include <stdint.h>

// ---- problem constants ----
#define NH      4
#define SF      128
#define BF      256
#define HD      32
#define NB      256    // WU*WU big tokens
#define NS      64     // W*W small tokens
#define NBATCH  1024

typedef short bf16x8 __attribute__((ext_vector_type(8)));
typedef float f32x4  __attribute__((ext_vector_type(4)));

// ---- ws layout (bytes) ----
#define WEFFT_OFF 0        // short[128*256]  (WeffT[n][k], scale*log2e folded)
#define BEFF_OFF  65536    // float[128]
#define WKVT_OFF  66048    // short[256*128]  (WkvT[n][k]; n<128 K-proj, n>=128 V-proj)
#define W2T_OFF   131584   // short[256*128]  (W2T[n][k])
#define BMATT_OFF 197120   // float[4][256 q][64 key]  (* log2e)

// ---- LDS layout (bytes), total 65536 ----
#define LDS_SK  0          // 16KB: small_x stage -> K  [64 tok][128 f] bf16, swz256
#define LDS_SVT 16384      // 16KB: V^T [128 f][64 tok] bf16, swz128
#define LDS_R3  32768      // 32KB: big stage dbuf (2x16KB) -> sQ [128][128] -> sP (8x4KB) -> sO [128][128]
#define LDS_TOTAL 65536

__device__ __forceinline__ short f2b(float x){
  uint32_t u = __float_as_uint(x);
  u += 0x7fff + ((u >> 16) & 1);
  return (short)(u >> 16);
}
__device__ __forceinline__ uint32_t cvt_pk_bf16(float lo, float hi){
  uint32_t r;
  asm("v_cvt_pk_bf16_f32 %0, %1, %2" : "=v"(r) : "v"(lo), "v"(hi));
  return r;
}
__device__ __forceinline__ int swz256(int row, int byteInRow){
  return row * 256 + (byteInRow ^ ((row & 7) << 4));
}
__device__ __forceinline__ int swz128(int row, int byteInRow){
  return row * 128 + (byteInRow ^ ((row & 7) << 4));
}

// =====================================================================
// prep kernel
// =====================================================================
__global__ void cowin_prep(const float* __restrict__ W1, const float* __restrict__ b1,
                           const float* __restrict__ Wqkv, const float* __restrict__ bqkv,
                           const float* __restrict__ W2, const float* __restrict__ tbl,
                           void* ws)
{
  short* weffT = (short*)((char*)ws + WEFFT_OFF);
  float* beff  = (float*)((char*)ws + BEFF_OFF);
  short* wkvT  = (short*)((char*)ws + WKVT_OFF);
  short* w2T   = (short*)((char*)ws + W2T_OFF);
  float* bmatT = (float*)((char*)ws + BMATT_OFF);
  const float L2E = 1.4426950408889634f;
  const float QS  = 0.17677669529663687f * L2E;   // HD^-0.5 * log2e

  int bid = blockIdx.x, t = threadIdx.x;
  if (bid < 128){                        // WeffT: n = bid, k = t
    int n = bid, k = t;
    float acc = 0.f;
    for (int c = 0; c < SF; ++c) acc += W1[k * SF + c] * Wqkv[c * (3*SF) + n];
    weffT[n * 256 + k] = f2b(acc * QS);
  } else if (bid == 128){
    if (t < 128){
      int n = t;
      float acc = bqkv[n];
      for (int c = 0; c < SF; ++c) acc += b1[c] * Wqkv[c * (3*SF) + n];
      beff[n] = acc * QS;
    }
  } else if (bid < 145){                 // WkvT: 32768 elems
    int base = (bid - 129) * 2048 + t * 8;
    for (int j = 0; j < 8; ++j){
      int i = base + j, n = i >> 7, k = i & 127;
      wkvT[i] = f2b(Wqkv[k * (3*SF) + SF + n]);
    }
  } else if (bid < 161){                 // W2T: 32768 elems
    int base = (bid - 145) * 2048 + t * 8;
    for (int j = 0; j < 8; ++j){
      int i = base + j, n = i >> 7, k = i & 127;
      w2T[i] = f2b(W2[k * BF + n]);
    }
  } else {                               // BmatT[h][q][key]: 65536 elems
    int i = (bid - 161) * 256 + t;
    int h = i >> 14, q = (i >> 6) & 255, key = i & 63;
    int qh = q >> 4, qw = q & 15, kh = key >> 3, kw = key & 7;
    int idx = (qh - kh + 7) * 15 + (qw - kw + 7);
    bmatT[i] = tbl[idx * 4 + h] * L2E;
  }
}

// =====================================================================
// fused main: 512 persistent-ish blocks x 4 tiles; tile = (batch, q-half).
// 512 thr = 8 waves. K/V reused across the two halves of a batch.
// =====================================================================
__global__ __launch_bounds__(512, 4) void cowin_main(
    const float* __restrict__ big_x, const float* __restrict__ small_x,
    const float* __restrict__ bqkv,  const float* __restrict__ b2,
    const void* __restrict__ ws, float* __restrict__ out)
{
  extern __shared__ char smem[];
  const short* weffT = (const short*)((const char*)ws + WEFFT_OFF);
  const float* beff  = (const float*)((const char*)ws + BEFF_OFF);
  const short* wkvT  = (const short*)((const char*)ws + WKVT_OFF);
  const short* w2T   = (const short*)((const char*)ws + W2T_OFF);
  const float* bmatT = (const float*)((const char*)ws + BMATT_OFF);

  const int wg  = blockIdx.x;
  const int swz = (wg & 7) * 64 + (wg >> 3);     // bijective XCD swizzle (512%8==0)
  const int t    = threadIdx.x;
  const int w    = t >> 6;          // wave id 0..7
  const int lane = t & 63;
  const int li   = lane & 15;
  const int g    = lane >> 4;
  const int h  = w & 3;             // head (attn phases)
  const int qh = w >> 2;            // q-half-of-128 (attn phases)

  const f32x4 vzero = {0.f, 0.f, 0.f, 0.f};

  const int tok = t >> 3, p = t & 7;            // small staging coords
  const int qrow = t >> 2, qq = (t & 3) * 16;   // big staging coords

  // ---- prologue: issue tile-0 loads ----
  float4 sv[4], ld[4];
  {
    int b0 = swz * 2;
    const float* sx = small_x + (size_t)b0 * (NS * SF);
    const float4* s0 = (const float4*)(sx + tok * SF + p * 16);
    #pragma unroll
    for (int i = 0; i < 4; ++i) sv[i] = s0[i];
    const float* bx0 = big_x + (size_t)b0 * NB * BF;
    const float4* s1 = (const float4*)(bx0 + qrow * BF + qq);
    #pragma unroll
    for (int i = 0; i < 4; ++i) ld[i] = s1[i];
  }

  for (int j = 0; j < 4; ++j){
    const int b  = swz * 2 + (j >> 1);
    const int hf = j & 1;
    const float* bx = big_x + (size_t)b * NB * BF + (size_t)hf * 128 * BF;

    __syncthreads();   // prev tile's LDS reads all done

    // ---------- A': stage small (even tiles only) + big chunk0; issue chunk1 ----------
    if (hf == 0){
      uint32_t pk[8];
      #pragma unroll
      for (int i = 0; i < 4; ++i){
        pk[2*i]   = cvt_pk_bf16(sv[i].x, sv[i].y);
        pk[2*i+1] = cvt_pk_bf16(sv[i].z, sv[i].w);
      }
      #pragma unroll
      for (int c = 0; c < 2; ++c){
        uint4 u; u.x = pk[c*4]; u.y = pk[c*4+1]; u.z = pk[c*4+2]; u.w = pk[c*4+3];
        *(uint4*)(smem + LDS_SK + swz256(tok, p * 32 + c * 16)) = u;
      }
    }
    {
      uint32_t pk[8];
      #pragma unroll
      for (int i = 0; i < 4; ++i){
        pk[2*i]   = cvt_pk_bf16(ld[i].x, ld[i].y);
        pk[2*i+1] = cvt_pk_bf16(ld[i].z, ld[i].w);
      }
      #pragma unroll
      for (int c = 0; c < 2; ++c){
        uint4 u; u.x = pk[c*4]; u.y = pk[c*4+1]; u.z = pk[c*4+2]; u.w = pk[c*4+3];
        *(uint4*)(smem + LDS_R3 + swz128(qrow, qq * 2 + c * 16)) = u;
      }
      const float4* s_ = (const float4*)(bx + qrow * BF + 64 + qq);
      #pragma unroll
      for (int i = 0; i < 4; ++i) ld[i] = s_[i];
    }
    __syncthreads();

    // ---------- B+C: KV GEMM + K/V^T writes (even tiles only) ----------
    if (hf == 0){
      f32x4 kv8[8];
      #pragma unroll
      for (int i = 0; i < 8; ++i) kv8[i] = vzero;

      if (w < 4){
        // K-waves: D[feat][tok] = mfma(wkvT_frag, sX_frag)
        #pragma unroll
        for (int ks = 0; ks < 4; ++ks){
          bf16x8 a2[2];
          #pragma unroll
          for (int mf = 0; mf < 2; ++mf)
            a2[mf] = *(const bf16x8*)(wkvT + (w*32 + mf*16 + li) * 128 + ks*32 + g*8);
          #pragma unroll
          for (int n4 = 0; n4 < 4; ++n4){
            bf16x8 b4 = *(const bf16x8*)(smem + LDS_SK + swz256(n4*16 + li, (ks*32 + g*8) * 2));
            #pragma unroll
            for (int mf = 0; mf < 2; ++mf)
              kv8[mf*4+n4] = __builtin_amdgcn_mfma_f32_16x16x32_bf16(a2[mf], b4, kv8[mf*4+n4], 0, 0, 0);
          }
        }
      } else {
        // V-waves: D[tok][feat] = mfma(sX_frag, wkvT_frag)
        #pragma unroll
        for (int ks = 0; ks < 4; ++ks){
          bf16x8 afr[4];
          #pragma unroll
          for (int m = 0; m < 4; ++m)
            afr[m] = *(const bf16x8*)(smem + LDS_SK + swz256(m*16 + li, (ks*32 + g*8) * 2));
          #pragma unroll
          for (int n2 = 0; n2 < 2; ++n2){
            int n = w * 32 + n2 * 16 + li;   // >=128 -> V rows of wkvT
            bf16x8 bfr = *(const bf16x8*)(wkvT + n * 128 + ks*32 + g*8);
            #pragma unroll
            for (int m = 0; m < 4; ++m)
              kv8[m*2+n2] = __builtin_amdgcn_mfma_f32_16x16x32_bf16(afr[m], bfr, kv8[m*2+n2], 0, 0, 0);
          }
        }
      }
      __syncthreads();   // sX reads done

      if (w < 4){
        #pragma unroll
        for (int mf = 0; mf < 2; ++mf){
          int f0 = w*32 + mf*16 + g*4;
          f32x4 bb = *(const f32x4*)(bqkv + SF + f0);
          #pragma unroll
          for (int n4 = 0; n4 < 4; ++n4){
            f32x4 vv = kv8[mf*4+n4];
            uint2 u;
            u.x = cvt_pk_bf16(vv[0] + bb[0], vv[1] + bb[1]);
            u.y = cvt_pk_bf16(vv[2] + bb[2], vv[3] + bb[3]);
            *(uint2*)(smem + LDS_SK + swz256(n4*16 + li, f0 * 2)) = u;
          }
        }
      } else {
        #pragma unroll
        for (int n2 = 0; n2 < 2; ++n2){
          int feat = (w-4)*32 + n2*16 + li;
          float bias = bqkv[2*SF + feat];
          #pragma unroll
          for (int m = 0; m < 4; ++m){
            f32x4 vv = kv8[m*2+n2];
            uint2 u;
            u.x = cvt_pk_bf16(vv[0] + bias, vv[1] + bias);
            u.y = cvt_pk_bf16(vv[2] + bias, vv[3] + bias);
            *(uint2*)(smem + LDS_SVT + swz128(feat, (m*16 + g*4) * 2)) = u;
          }
        }
      }
      // visibility of K/V^T for E/F covered by the D-loop barriers
    }

    // ---------- D: Q^T GEMM: D[feat][q] over K=256, 4 chunks, LDS dbuf ----------
    f32x4 qacc[8];
    #pragma unroll
    for (int m = 0; m < 8; ++m) qacc[m] = vzero;

    for (int kc = 0; kc < 4; ++kc){
      __syncthreads();
      if (kc < 3){
        uint32_t pk[8];
        #pragma unroll
        for (int i = 0; i < 4; ++i){
          pk[2*i]   = cvt_pk_bf16(ld[i].x, ld[i].y);
          pk[2*i+1] = cvt_pk_bf16(ld[i].z, ld[i].w);
        }
        char* bufn = smem + LDS_R3 + ((kc + 1) & 1) * 16384;
        #pragma unroll
        for (int c = 0; c < 2; ++c){
          uint4 u; u.x = pk[c*4]; u.y = pk[c*4+1]; u.z = pk[c*4+2]; u.w = pk[c*4+3];
          *(uint4*)(bufn + swz128(qrow, qq * 2 + c * 16)) = u;
        }
        if (kc < 2){
          const float4* s_ = (const float4*)(bx + qrow * BF + (kc + 2) * 64 + qq);
          #pragma unroll
          for (int i = 0; i < 4; ++i) ld[i] = s_[i];
        }
      } else if (j == 1){
        // prefetch small_x for tile 2 (next even tile)
        const float* sx2 = small_x + (size_t)(swz * 2 + 1) * (NS * SF);
        const float4* s0 = (const float4*)(sx2 + tok * SF + p * 16);
        #pragma unroll
        for (int i = 0; i < 4; ++i) sv[i] = s0[i];
      }
      const char* buf = smem + LDS_R3 + (kc & 1) * 16384;
      #pragma unroll
      for (int ks = 0; ks < 2; ++ks){
        bf16x8 a = *(const bf16x8*)(weffT + (w*16 + li) * 256 + kc*64 + ks*32 + g*8);
        #pragma unroll
        for (int nt = 0; nt < 8; ++nt){
          bf16x8 bq = *(const bf16x8*)(buf + swz128(nt*16 + li, (ks*32 + g*8) * 2));
          qacc[nt] = __builtin_amdgcn_mfma_f32_16x16x32_bf16(a, bq, qacc[nt], 0, 0, 0);
        }
      }
    }
    __syncthreads();   // stage reads done; R3 -> sQ

    // ---------- D': Q^T acc -> sQ[q][feat] (b64 writes) ----------
    {
      f32x4 be = *(const f32x4*)(beff + w*16 + g*4);
      #pragma unroll
      for (int nt = 0; nt < 8; ++nt){
        f32x4 vv = qacc[nt];
        uint2 u;
        u.x = cvt_pk_bf16(vv[0] + be[0], vv[1] + be[1]);
        u.y = cvt_pk_bf16(vv[2] + be[2], vv[3] + be[3]);
        *(uint2*)(smem + LDS_R3 + swz256(nt*16 + li, (w*16 + g*4) * 2)) = u;
      }
    }
    __syncthreads();

    // ---------- E: S^T = K . Q^T ; wave=(h,qh): 4(key)x4(q) tiles ----------
    f32x4 sacc[4][4];
    #pragma unroll
    for (int m = 0; m < 4; ++m)
      #pragma unroll
      for (int n = 0; n < 4; ++n) sacc[m][n] = vzero;
    {
      bf16x8 afr[4];
      #pragma unroll
      for (int m = 0; m < 4; ++m)
        afr[m] = *(const bf16x8*)(smem + LDS_SK + swz256(m*16 + li, (h*32 + g*8) * 2));
      #pragma unroll
      for (int n = 0; n < 4; ++n){
        bf16x8 bfr = *(const bf16x8*)(smem + LDS_R3 + swz256(qh*64 + n*16 + li, (h*32 + g*8) * 2));
        #pragma unroll
        for (int m = 0; m < 4; ++m)
          sacc[m][n] = __builtin_amdgcn_mfma_f32_16x16x32_bf16(afr[m], bfr, sacc[m][n], 0, 0, 0);
      }
    }
    __syncthreads();   // K/sQ reads done -> R3 reusable for sP

    // bias add (vector loads from bmatT[h][q][key])
    #pragma unroll
    for (int n = 0; n < 4; ++n){
      const float* bm = bmatT + ((size_t)(h * 256 + hf*128 + qh*64 + n*16 + li)) * 64;
      #pragma unroll
      for (int m = 0; m < 4; ++m){
        f32x4 bb = *(const f32x4*)(bm + m*16 + g*4);
        sacc[m][n] += bb;
      }
    }

    // softmax over keys, per q (log2-domain)
    float sm[4];
    #pragma unroll
    for (int n = 0; n < 4; ++n){
      float mx = sacc[0][n][0];
      #pragma unroll
      for (int m = 0; m < 4; ++m)
        #pragma unroll
        for (int r = 0; r < 4; ++r) mx = fmaxf(mx, sacc[m][n][r]);
      mx = fmaxf(mx, __shfl_xor(mx, 16));
      mx = fmaxf(mx, __shfl_xor(mx, 32));
      float s0 = 0.f;
      #pragma unroll
      for (int m = 0; m < 4; ++m)
        #pragma unroll
        for (int r = 0; r < 4; ++r){
          float e = __builtin_amdgcn_exp2f(sacc[m][n][r] - mx);
          sacc[m][n][r] = e;
          s0 += e;
        }
      s0 += __shfl_xor(s0, 16);
      s0 += __shfl_xor(s0, 32);
      sm[n] = __builtin_amdgcn_rcpf(s0);
    }

    // ---------- F: P -> sP (wave-private 4KB), PV: O^T = V^T . P^T ----------
    f32x4 oacc[2][2][2];
    #pragma unroll
    for (int hl = 0; hl < 2; ++hl)
      #pragma unroll
      for (int m2 = 0; m2 < 2; ++m2)
        #pragma unroll
        for (int n4 = 0; n4 < 2; ++n4) oacc[hl][m2][n4] = vzero;

    char* sp = smem + LDS_R3 + w * 4096;   // [32 q][64 key] bf16 swz128
    #pragma unroll
    for (int hl = 0; hl < 2; ++hl){
      #pragma unroll
      for (int n4 = 0; n4 < 2; ++n4){
        int n = hl * 2 + n4;
        #pragma unroll
        for (int m = 0; m < 4; ++m){
          uint2 u;
          u.x = cvt_pk_bf16(sacc[m][n][0], sacc[m][n][1]);
          u.y = cvt_pk_bf16(sacc[m][n][2], sacc[m][n][3]);
          *(uint2*)(sp + swz128(n4 * 16 + li, (m * 16 + g * 4) * 2)) = u;
        }
      }
      #pragma unroll
      for (int kk = 0; kk < 2; ++kk){
        bf16x8 afr2[2];
        #pragma unroll
        for (int m2 = 0; m2 < 2; ++m2)
          afr2[m2] = *(const bf16x8*)(smem + LDS_SVT + swz128(h*32 + m2*16 + li, (kk*32 + g*8) * 2));
        #pragma unroll
        for (int n4 = 0; n4 < 2; ++n4){
          bf16x8 bfr = *(const bf16x8*)(sp + swz128(n4 * 16 + li, (kk*32 + g*8) * 2));
          #pragma unroll
          for (int m2 = 0; m2 < 2; ++m2)
            oacc[hl][m2][n4] = __builtin_amdgcn_mfma_f32_16x16x32_bf16(afr2[m2], bfr, oacc[hl][m2][n4], 0, 0, 0);
        }
      }
    }
    __syncthreads();   // V^T/sP reads done -> R3 reusable for sO

    // O^T / sum -> sO [128 q][128 f] bf16 swz256 in R3
    #pragma unroll
    for (int hl = 0; hl < 2; ++hl)
      #pragma unroll
      for (int m2 = 0; m2 < 2; ++m2)
        #pragma unroll
        for (int n4 = 0; n4 < 2; ++n4){
          float rs = sm[hl * 2 + n4];
          f32x4 vv = oacc[hl][m2][n4];
          uint2 u;
          u.x = cvt_pk_bf16(vv[0] * rs, vv[1] * rs);
          u.y = cvt_pk_bf16(vv[2] * rs, vv[3] * rs);
          int q = qh * 64 + hl * 32 + n4 * 16 + li;
          *(uint2*)(smem + LDS_R3 + swz256(q, (h*32 + m2*16 + g*4) * 2)) = u;
        }
    __syncthreads();

    // prefetch next tile's big chunk0 (overlaps G + epilogue)
    if (j < 3){
      int b2_ = swz * 2 + ((j + 1) >> 1);
      int hf2 = (j + 1) & 1;
      const float* bx2 = big_x + (size_t)b2_ * NB * BF + (size_t)hf2 * 128 * BF;
      const float4* s1 = (const float4*)(bx2 + qrow * BF + qq);
      #pragma unroll
      for (int i = 0; i < 4; ++i) ld[i] = s1[i];
    }

    // ---------- G: out^T tiles = mfma(w2T, sO) -> float4 stores ----------
    f32x4 facc[2][8];
    #pragma unroll
    for (int mo = 0; mo < 2; ++mo)
      #pragma unroll
      for (int nt = 0; nt < 8; ++nt) facc[mo][nt] = vzero;

    #pragma unroll
    for (int kc = 0; kc < 4; ++kc){
      bf16x8 a2[2];
      #pragma unroll
      for (int mo = 0; mo < 2; ++mo)
        a2[mo] = *(const bf16x8*)(w2T + (w*32 + mo*16 + li) * 128 + kc*32 + g*8);
      #pragma unroll
      for (int nt = 0; nt < 8; ++nt){
        bf16x8 b8 = *(const bf16x8*)(smem + LDS_R3 + swz256(nt*16 + li, (kc*32 + g*8) * 2));
        #pragma unroll
        for (int mo = 0; mo < 2; ++mo)
          facc[mo][nt] = __builtin_amdgcn_mfma_f32_16x16x32_bf16(a2[mo], b8, facc[mo][nt], 0, 0, 0);
      }
    }

    float* op = out + (size_t)b * NB * BF + (size_t)hf * 128 * BF;
    #pragma unroll
    for (int mo = 0; mo < 2; ++mo){
      int c0 = w*32 + mo*16 + g*4;
      f32x4 bb = *(const f32x4*)(b2 + c0);
      #pragma unroll
      for (int nt = 0; nt < 8; ++nt){
        f32x4 vv = facc[mo][nt] + bb;
        *(f32x4*)(op + (size_t)(nt*16 + li) * BF + c0) = vv;
      }
    }
  } // tile loop
}

extern "C" void kernel_launch(void* const* d_in, const int* in_sizes, int n_in,
                              void* d_out, int out_size, void* d_ws, size_t ws_size,
                              hipStream_t stream)
{
  const float* big_x   = (const float*)d_in[0];
  const float* small_x = (const float*)d_in[1];
  const float* W1      = (const float*)d_in[2];
  const float* b1      = (const float*)d_in[3];
  const float* Wqkv    = (const float*)d_in[4];
  const float* bqkv    = (const float*)d_in[5];
  const float* W2      = (const float*)d_in[6];
  const float* b2      = (const float*)d_in[7];
  const float* tbl     = (const float*)d_in[8];
  float* out = (float*)d_out;

  (void)in_sizes; (void)n_in; (void)out_size; (void)ws_size;

  cowin_prep<<<417, 256, 0, stream>>>(W1, b1, Wqkv, bqkv, W2, tbl, d_ws);

  hipFuncSetAttribute(reinterpret_cast<const void*>(cowin_main),
                      hipFuncAttributeMaxDynamicSharedMemorySize, LDS_TOTAL);
  cowin_main<<<512, 512, LDS_TOTAL, stream>>>(big_x, small_x, bqkv, b2, d_ws, out);
}

// Round 4
// 208.165 us; speedup vs baseline: 1.5940x; 1.5940x over previous
//
#include <hip/hip_runtime.h>
#include <stdint.h>

// ---- problem constants ----
#define NH      4
#define SF      128
#define BF      256
#define HD      32
#define NB      256    // WU*WU big tokens
#define NS      64     // W*W small tokens
#define NBATCH  1024

typedef short bf16x8 __attribute__((ext_vector_type(8)));
typedef float f32x4  __attribute__((ext_vector_type(4)));

// ---- ws layout (bytes) ----
#define WEFFT_OFF 0        // short[128*256]  (WeffT[n][k], scale*log2e folded)
#define BEFF_OFF  65536    // float[128]
#define WKVT_OFF  66048    // short[256*128]  (WkvT[n][k]; n<128 K-proj, n>=128 V-proj)
#define W2T_OFF   131584   // short[256*128]  (W2T[n][k])
#define BMATT_OFF 197120   // float[4][256 q][64 key]  (* log2e)
#define KV_OFF    459264   // per batch 32KB: K [4][64 tok][32 f] bf16 ; V^T [4][32 f][64 tok] bf16
#define WS_NEED   (KV_OFF + (size_t)NBATCH * 32768u)

__device__ __forceinline__ short f2b(float x){
  uint32_t u = __float_as_uint(x);
  u += 0x7fff + ((u >> 16) & 1);
  return (short)(u >> 16);
}
__device__ __forceinline__ uint32_t cvt_pk_bf16(float lo, float hi){
  uint32_t r;
  asm("v_cvt_pk_bf16_f32 %0, %1, %2" : "=v"(r) : "v"(lo), "v"(hi));
  return r;
}
__device__ __forceinline__ int swz256(int row, int byteInRow){
  return row * 256 + (byteInRow ^ ((row & 7) << 4));
}
__device__ __forceinline__ int swz128(int row, int byteInRow){
  return row * 128 + (byteInRow ^ ((row & 7) << 4));
}

// =====================================================================
// prep kernel (weights -> bf16 transposed; bias matrix)
// =====================================================================
__global__ void cowin_prep(const float* __restrict__ W1, const float* __restrict__ b1,
                           const float* __restrict__ Wqkv, const float* __restrict__ bqkv,
                           const float* __restrict__ W2, const float* __restrict__ tbl,
                           void* ws)
{
  short* weffT = (short*)((char*)ws + WEFFT_OFF);
  float* beff  = (float*)((char*)ws + BEFF_OFF);
  short* wkvT  = (short*)((char*)ws + WKVT_OFF);
  short* w2T   = (short*)((char*)ws + W2T_OFF);
  float* bmatT = (float*)((char*)ws + BMATT_OFF);
  const float L2E = 1.4426950408889634f;
  const float QS  = 0.17677669529663687f * L2E;   // HD^-0.5 * log2e

  int bid = blockIdx.x, t = threadIdx.x;
  if (bid < 128){                        // WeffT: n = bid, k = t
    int n = bid, k = t;
    float acc = 0.f;
    for (int c = 0; c < SF; ++c) acc += W1[k * SF + c] * Wqkv[c * (3*SF) + n];
    weffT[n * 256 + k] = f2b(acc * QS);
  } else if (bid == 128){
    if (t < 128){
      int n = t;
      float acc = bqkv[n];
      for (int c = 0; c < SF; ++c) acc += b1[c] * Wqkv[c * (3*SF) + n];
      beff[n] = acc * QS;
    }
  } else if (bid < 145){                 // WkvT: 32768 elems
    int base = (bid - 129) * 2048 + t * 8;
    for (int j = 0; j < 8; ++j){
      int i = base + j, n = i >> 7, k = i & 127;
      wkvT[i] = f2b(Wqkv[k * (3*SF) + SF + n]);
    }
  } else if (bid < 161){                 // W2T: 32768 elems
    int base = (bid - 145) * 2048 + t * 8;
    for (int j = 0; j < 8; ++j){
      int i = base + j, n = i >> 7, k = i & 127;
      w2T[i] = f2b(W2[k * BF + n]);
    }
  } else {                               // BmatT[h][q][key]: 65536 elems
    int i = (bid - 161) * 256 + t;
    int h = i >> 14, q = (i >> 6) & 255, key = i & 63;
    int qh = q >> 4, qw = q & 15, kh = key >> 3, kw = key & 7;
    int idx = (qh - kh + 7) * 15 + (qw - kw + 7);
    bmatT[i] = tbl[idx * 4 + h] * L2E;
  }
}

// =====================================================================
// KV kernel: one block per batch. K/V GEMM -> ws in attention layout.
// =====================================================================
__global__ __launch_bounds__(256, 4) void cowin_kv(
    const float* __restrict__ small_x, const float* __restrict__ bqkv,
    void* __restrict__ ws)
{
  __shared__ __align__(16) char smem[32768];   // sX/sK @0 (16KB), sVT @16K
  const short* wkvT = (const short*)((const char*)ws + WKVT_OFF);
  char* kvb = (char*)ws + KV_OFF + (size_t)blockIdx.x * 32768;

  const int b = blockIdx.x;
  const int t = threadIdx.x, w = t >> 6, lane = t & 63, li = lane & 15, g = lane >> 4;
  const f32x4 vzero = {0.f, 0.f, 0.f, 0.f};

  // ---- stage small_x -> sX bf16 swz256 ----
  {
    int tok = t >> 2, seg = t & 3;
    const float4* src = (const float4*)(small_x + (size_t)b * (NS * SF) + tok * SF + seg * 32);
    float4 v[8];
    #pragma unroll
    for (int i = 0; i < 8; ++i) v[i] = src[i];
    uint32_t pk[16];
    #pragma unroll
    for (int i = 0; i < 8; ++i){
      pk[2*i]   = cvt_pk_bf16(v[i].x, v[i].y);
      pk[2*i+1] = cvt_pk_bf16(v[i].z, v[i].w);
    }
    #pragma unroll
    for (int c = 0; c < 4; ++c){
      uint4 u; u.x = pk[c*4]; u.y = pk[c*4+1]; u.z = pk[c*4+2]; u.w = pk[c*4+3];
      *(uint4*)(smem + swz256(tok, seg * 64 + c * 16)) = u;
    }
  }
  __syncthreads();

  // ---- GEMM ----
  f32x4 acc[4][4];
  #pragma unroll
  for (int m = 0; m < 4; ++m)
    #pragma unroll
    for (int n = 0; n < 4; ++n) acc[m][n] = vzero;

  if (w < 2){
    // K-waves: C[feat][tok] = mfma(wkvT rows feat, sX rows tok)
    #pragma unroll
    for (int ks = 0; ks < 4; ++ks){
      bf16x8 a4[4], b4[4];
      #pragma unroll
      for (int mf = 0; mf < 4; ++mf)
        a4[mf] = *(const bf16x8*)(wkvT + (w*64 + mf*16 + li) * 128 + ks*32 + g*8);
      #pragma unroll
      for (int n4 = 0; n4 < 4; ++n4)
        b4[n4] = *(const bf16x8*)(smem + swz256(n4*16 + li, ks*64 + g*16));
      #pragma unroll
      for (int mf = 0; mf < 4; ++mf)
        #pragma unroll
        for (int n4 = 0; n4 < 4; ++n4)
          acc[mf][n4] = __builtin_amdgcn_mfma_f32_16x16x32_bf16(a4[mf], b4[n4], acc[mf][n4], 0, 0, 0);
    }
  } else {
    // V-waves: C[tok][feat] = mfma(sX rows tok, wkvT rows 128+feat)
    #pragma unroll
    for (int ks = 0; ks < 4; ++ks){
      bf16x8 a4[4], b4[4];
      #pragma unroll
      for (int m = 0; m < 4; ++m)
        a4[m] = *(const bf16x8*)(smem + swz256(m*16 + li, ks*64 + g*16));
      #pragma unroll
      for (int n4 = 0; n4 < 4; ++n4)
        b4[n4] = *(const bf16x8*)(wkvT + (128 + (w-2)*64 + n4*16 + li) * 128 + ks*32 + g*8);
      #pragma unroll
      for (int m = 0; m < 4; ++m)
        #pragma unroll
        for (int n4 = 0; n4 < 4; ++n4)
          acc[m][n4] = __builtin_amdgcn_mfma_f32_16x16x32_bf16(a4[m], b4[n4], acc[m][n4], 0, 0, 0);
    }
  }
  __syncthreads();   // sX reads done

  if (w < 2){
    // write sK[tok][feat] @0
    #pragma unroll
    for (int mf = 0; mf < 4; ++mf){
      int f0 = w*64 + mf*16 + g*4;
      f32x4 bb = *(const f32x4*)(bqkv + SF + f0);
      #pragma unroll
      for (int n4 = 0; n4 < 4; ++n4){
        f32x4 vv = acc[mf][n4];
        uint2 u;
        u.x = cvt_pk_bf16(vv[0] + bb[0], vv[1] + bb[1]);
        u.y = cvt_pk_bf16(vv[2] + bb[2], vv[3] + bb[3]);
        *(uint2*)(smem + swz256(n4*16 + li, f0 * 2)) = u;
      }
    }
  } else {
    // write sVT[feat][tok] @16K
    #pragma unroll
    for (int n4 = 0; n4 < 4; ++n4){
      int feat = (w-2)*64 + n4*16 + li;
      float bias = bqkv[2*SF + feat];
      #pragma unroll
      for (int m = 0; m < 4; ++m){
        f32x4 vv = acc[m][n4];
        uint2 u;
        u.x = cvt_pk_bf16(vv[0] + bias, vv[1] + bias);
        u.y = cvt_pk_bf16(vv[2] + bias, vv[3] + bias);
        *(uint2*)(smem + 16384 + swz128(feat, (m*16 + g*4) * 2)) = u;
      }
    }
  }
  __syncthreads();

  // ---- copy out to attention layout ----
  // K: [h][tok][32f] bf16, 16B chunks: id = h*256 + tok*4 + c
  #pragma unroll
  for (int it = 0; it < 4; ++it){
    int id = it * 256 + t;
    int h = id >> 8, tok = (id >> 2) & 63, c = id & 3;
    uint4 v = *(const uint4*)(smem + swz256(tok, h*64 + c*16));
    *(uint4*)(kvb + id * 16) = v;
  }
  // V^T: [h][32f][64tok] bf16, 16B chunks: id = (h*32+f)*8 + c
  #pragma unroll
  for (int it = 0; it < 4; ++it){
    int id = it * 256 + t;
    int fg = id >> 3, c = id & 7;
    uint4 v = *(const uint4*)(smem + 16384 + swz128(fg, c*16));
    *(uint4*)(kvb + 16384 + id * 16) = v;
  }
}

// =====================================================================
// attention kernel: 4096 blocks x 256 thr; tile = 64 q rows of one batch.
// LDS 32KB: buf0@0(8K), buf1@8K, sQ@16K(16K); then sP(4x8K)@0; then sO@0(16K)
// =====================================================================
__global__ __launch_bounds__(256, 4) void cowin_attn(
    const float* __restrict__ big_x, const float* __restrict__ b2,
    const void* __restrict__ ws, float* __restrict__ out)
{
  __shared__ __align__(16) char smem[32768];
  const short* weffT = (const short*)((const char*)ws + WEFFT_OFF);
  const float* beff  = (const float*)((const char*)ws + BEFF_OFF);
  const short* w2T   = (const short*)((const char*)ws + W2T_OFF);
  const float* bmatT = (const float*)((const char*)ws + BMATT_OFF);

  const int b  = blockIdx.x >> 2;
  const int qt = blockIdx.x & 3;
  const char* kvb = (const char*)ws + KV_OFF + (size_t)b * 32768;

  const int t = threadIdx.x, w = t >> 6, lane = t & 63, li = lane & 15, g = lane >> 4;
  const int h = w;                       // head = wave
  const f32x4 vzero = {0.f, 0.f, 0.f, 0.f};

  const float* bx = big_x + ((size_t)b * NB + qt * 64) * BF;
  const int qrow = t >> 2, qq = (t & 3) * 16;

  // ---- prologue: issue chunk0 + chunk1 loads ----
  float4 ldA[4], ldB[4];
  {
    const float4* s0 = (const float4*)(bx + qrow * BF + qq);
    #pragma unroll
    for (int i = 0; i < 4; ++i) ldA[i] = s0[i];
    const float4* s1 = (const float4*)(bx + qrow * BF + 64 + qq);
    #pragma unroll
    for (int i = 0; i < 4; ++i) ldB[i] = s1[i];
  }

  auto STAGE = [&](float4* v, char* buf){
    uint32_t pk[8];
    #pragma unroll
    for (int i = 0; i < 4; ++i){
      pk[2*i]   = cvt_pk_bf16(v[i].x, v[i].y);
      pk[2*i+1] = cvt_pk_bf16(v[i].z, v[i].w);
    }
    #pragma unroll
    for (int c = 0; c < 2; ++c){
      uint4 u; u.x = pk[c*4]; u.y = pk[c*4+1]; u.z = pk[c*4+2]; u.w = pk[c*4+3];
      *(uint4*)(buf + swz128(qrow, qq * 2 + c * 16)) = u;
    }
  };
  auto ISSUE = [&](float4* v, int kc){
    const float4* s_ = (const float4*)(bx + qrow * BF + kc * 64 + qq);
    #pragma unroll
    for (int i = 0; i < 4; ++i) v[i] = s_[i];
  };

  f32x4 qacc[2][4];
  #pragma unroll
  for (int mf = 0; mf < 2; ++mf)
    #pragma unroll
    for (int nt = 0; nt < 4; ++nt) qacc[mf][nt] = vzero;

  auto MFMA_D = [&](const char* buf, int kc){
    #pragma unroll
    for (int ks = 0; ks < 2; ++ks){
      bf16x8 a2[2], bq[4];
      #pragma unroll
      for (int mf = 0; mf < 2; ++mf)
        a2[mf] = *(const bf16x8*)(weffT + (w*32 + mf*16 + li) * 256 + kc*64 + ks*32 + g*8);
      #pragma unroll
      for (int nt = 0; nt < 4; ++nt)
        bq[nt] = *(const bf16x8*)(buf + swz128(nt*16 + li, ks*64 + g*16));
      #pragma unroll
      for (int mf = 0; mf < 2; ++mf)
        #pragma unroll
        for (int nt = 0; nt < 4; ++nt)
          qacc[mf][nt] = __builtin_amdgcn_mfma_f32_16x16x32_bf16(a2[mf], bq[nt], qacc[mf][nt], 0, 0, 0);
    }
  };

  char* buf0 = smem;
  char* buf1 = smem + 8192;

  // ---- Phase D: Q^T GEMM over K=256, 4 chunks, dbuf ----
  STAGE(ldA, buf0);
  __syncthreads();
  STAGE(ldB, buf1); ISSUE(ldA, 2);
  MFMA_D(buf0, 0);
  __syncthreads();
  STAGE(ldA, buf0); ISSUE(ldB, 3);
  MFMA_D(buf1, 1);
  __syncthreads();
  STAGE(ldB, buf1);
  MFMA_D(buf0, 2);
  __syncthreads();
  MFMA_D(buf1, 3);

  // ---- D': Q^T (+beff) -> sQ[q][feat] bf16 swz256 @16K ----
  #pragma unroll
  for (int mf = 0; mf < 2; ++mf){
    int f0 = w*32 + mf*16 + g*4;
    f32x4 be = *(const f32x4*)(beff + f0);
    #pragma unroll
    for (int nt = 0; nt < 4; ++nt){
      f32x4 vv = qacc[mf][nt];
      uint2 u;
      u.x = cvt_pk_bf16(vv[0] + be[0], vv[1] + be[1]);
      u.y = cvt_pk_bf16(vv[2] + be[2], vv[3] + be[3]);
      *(uint2*)(smem + 16384 + swz256(nt*16 + li, f0 * 2)) = u;
    }
  }
  __syncthreads();

  // ---- E: S^T = K . Q^T (K from global kv ws) ----
  f32x4 sacc[4][4];
  #pragma unroll
  for (int m = 0; m < 4; ++m)
    #pragma unroll
    for (int n = 0; n < 4; ++n) sacc[m][n] = vzero;
  {
    bf16x8 afr[4], bfr[4];
    #pragma unroll
    for (int m = 0; m < 4; ++m)
      afr[m] = *(const bf16x8*)(kvb + (h*64 + m*16 + li) * 64 + g*16);
    #pragma unroll
    for (int n = 0; n < 4; ++n)
      bfr[n] = *(const bf16x8*)(smem + 16384 + swz256(n*16 + li, h*64 + g*16));
    #pragma unroll
    for (int m = 0; m < 4; ++m)
      #pragma unroll
      for (int n = 0; n < 4; ++n)
        sacc[m][n] = __builtin_amdgcn_mfma_f32_16x16x32_bf16(afr[m], bfr[n], sacc[m][n], 0, 0, 0);
  }

  // bias add: [key = m*16+g*4+r][q = qt*64 + n*16+li]
  #pragma unroll
  for (int n = 0; n < 4; ++n){
    const float* bm = bmatT + ((size_t)(h * 256 + qt*64 + n*16 + li)) * 64;
    #pragma unroll
    for (int m = 0; m < 4; ++m)
      sacc[m][n] += *(const f32x4*)(bm + m*16 + g*4);
  }

  // softmax over 64 keys per q (log2-domain)
  float sm[4];
  #pragma unroll
  for (int n = 0; n < 4; ++n){
    float mx = sacc[0][n][0];
    #pragma unroll
    for (int m = 0; m < 4; ++m)
      #pragma unroll
      for (int r = 0; r < 4; ++r) mx = fmaxf(mx, sacc[m][n][r]);
    mx = fmaxf(mx, __shfl_xor(mx, 16));
    mx = fmaxf(mx, __shfl_xor(mx, 32));
    float s0 = 0.f;
    #pragma unroll
    for (int m = 0; m < 4; ++m)
      #pragma unroll
      for (int r = 0; r < 4; ++r){
        float e = __builtin_amdgcn_exp2f(sacc[m][n][r] - mx);
        sacc[m][n][r] = e;
        s0 += e;
      }
    s0 += __shfl_xor(s0, 16);
    s0 += __shfl_xor(s0, 32);
    sm[n] = __builtin_amdgcn_rcpf(s0);
  }
  __syncthreads();   // sQ reads done -> whole LDS reusable for sP

  // ---- F: P -> sP (wave-private 8KB), PV: O^T = V^T . P^T ----
  char* sp = smem + w * 8192;   // [64 q][64 key] bf16 swz128
  #pragma unroll
  for (int n = 0; n < 4; ++n)
    #pragma unroll
    for (int m = 0; m < 4; ++m){
      uint2 u;
      u.x = cvt_pk_bf16(sacc[m][n][0], sacc[m][n][1]);
      u.y = cvt_pk_bf16(sacc[m][n][2], sacc[m][n][3]);
      *(uint2*)(sp + swz128(n*16 + li, (m*16 + g*4) * 2)) = u;
    }

  f32x4 oacc[2][4];
  #pragma unroll
  for (int m2 = 0; m2 < 2; ++m2)
    #pragma unroll
    for (int n = 0; n < 4; ++n) oacc[m2][n] = vzero;

  #pragma unroll
  for (int kk = 0; kk < 2; ++kk){
    bf16x8 va[2], pb[4];
    #pragma unroll
    for (int m2 = 0; m2 < 2; ++m2)
      va[m2] = *(const bf16x8*)(kvb + 16384 + (h*32 + m2*16 + li) * 128 + kk*64 + g*16);
    #pragma unroll
    for (int n = 0; n < 4; ++n)
      pb[n] = *(const bf16x8*)(sp + swz128(n*16 + li, kk*64 + g*16));
    #pragma unroll
    for (int m2 = 0; m2 < 2; ++m2)
      #pragma unroll
      for (int n = 0; n < 4; ++n)
        oacc[m2][n] = __builtin_amdgcn_mfma_f32_16x16x32_bf16(va[m2], pb[n], oacc[m2][n], 0, 0, 0);
  }
  __syncthreads();   // all waves done with their sP -> sO may overwrite @0

  // ---- sO [64 q][128 f] bf16 swz256 @0 ----
  #pragma unroll
  for (int m2 = 0; m2 < 2; ++m2)
    #pragma unroll
    for (int n = 0; n < 4; ++n){
      float rs = sm[n];
      f32x4 vv = oacc[m2][n];
      uint2 u;
      u.x = cvt_pk_bf16(vv[0] * rs, vv[1] * rs);
      u.y = cvt_pk_bf16(vv[2] * rs, vv[3] * rs);
      *(uint2*)(smem + swz256(n*16 + li, (h*32 + m2*16 + g*4) * 2)) = u;
    }
  __syncthreads();

  // ---- G: out^T tiles = mfma(w2T, sO), two passes to cap VGPR ----
  float* op = out + ((size_t)b * NB + qt * 64) * BF;
  #pragma unroll
  for (int p = 0; p < 2; ++p){
    f32x4 facc[2][4];
    #pragma unroll
    for (int mo = 0; mo < 2; ++mo)
      #pragma unroll
      for (int nt = 0; nt < 4; ++nt) facc[mo][nt] = vzero;

    #pragma unroll
    for (int kc = 0; kc < 4; ++kc){
      bf16x8 a2[2], b8[4];
      #pragma unroll
      for (int mo = 0; mo < 2; ++mo)
        a2[mo] = *(const bf16x8*)(w2T + (w*64 + p*32 + mo*16 + li) * 128 + kc*32 + g*8);
      #pragma unroll
      for (int nt = 0; nt < 4; ++nt)
        b8[nt] = *(const bf16x8*)(smem + swz256(nt*16 + li, kc*64 + g*16));
      #pragma unroll
      for (int mo = 0; mo < 2; ++mo)
        #pragma unroll
        for (int nt = 0; nt < 4; ++nt)
          facc[mo][nt] = __builtin_amdgcn_mfma_f32_16x16x32_bf16(a2[mo], b8[nt], facc[mo][nt], 0, 0, 0);
    }
    #pragma unroll
    for (int mo = 0; mo < 2; ++mo){
      int c0 = w*64 + p*32 + mo*16 + g*4;
      f32x4 bb = *(const f32x4*)(b2 + c0);
      #pragma unroll
      for (int nt = 0; nt < 4; ++nt){
        f32x4 vv = facc[mo][nt] + bb;
        __builtin_nontemporal_store(vv, (f32x4*)(op + (size_t)(nt*16 + li) * BF + c0));
      }
    }
  }
}

// =====================================================================
// fallback fused kernel (only if ws too small for the KV cache):
// de-looped R3 structure, 2048 blocks x 512 thr, 64KB dynamic LDS.
// =====================================================================
#define LDS_SK  0
#define LDS_SVT 16384
#define LDS_R3  32768
#define LDS_TOTAL 65536

__global__ __launch_bounds__(512, 4) void cowin_main_fb(
    const float* __restrict__ big_x, const float* __restrict__ small_x,
    const float* __restrict__ bqkv,  const float* __restrict__ b2,
    const void* __restrict__ ws, float* __restrict__ out)
{
  extern __shared__ char smem[];
  const short* weffT = (const short*)((const char*)ws + WEFFT_OFF);
  const float* beff  = (const float*)((const char*)ws + BEFF_OFF);
  const short* wkvT  = (const short*)((const char*)ws + WKVT_OFF);
  const short* w2T   = (const short*)((const char*)ws + W2T_OFF);
  const float* bmatT = (const float*)((const char*)ws + BMATT_OFF);

  const int bid = blockIdx.x;
  const int b  = bid >> 1;
  const int hf = bid & 1;
  const int t    = threadIdx.x;
  const int w    = t >> 6;
  const int lane = t & 63;
  const int li   = lane & 15;
  const int g    = lane >> 4;
  const int h  = w & 3;
  const int qh = w >> 2;

  const f32x4 vzero = {0.f, 0.f, 0.f, 0.f};
  const int tok = t >> 3, p = t & 7;
  const int qrow = t >> 1, qq = (t & 1) * 32;

  const float* bx = big_x + (size_t)b * NB * BF + (size_t)hf * 128 * BF;

  // stage small + big chunk0; issue chunk1
  float4 ld[4];
  {
    const float* sx = small_x + (size_t)b * (NS * SF);
    const float4* s0 = (const float4*)(sx + tok * SF + p * 16);
    float4 sv[4];
    #pragma unroll
    for (int i = 0; i < 4; ++i) sv[i] = s0[i];
    const float4* s1 = (const float4*)(bx + qrow * BF + qq);
    float4 bv[8];
    #pragma unroll
    for (int i = 0; i < 8; ++i) bv[i] = s1[i];
    uint32_t pk[8];
    #pragma unroll
    for (int i = 0; i < 4; ++i){
      pk[2*i]   = cvt_pk_bf16(sv[i].x, sv[i].y);
      pk[2*i+1] = cvt_pk_bf16(sv[i].z, sv[i].w);
    }
    #pragma unroll
    for (int c = 0; c < 2; ++c){
      uint4 u; u.x = pk[c*4]; u.y = pk[c*4+1]; u.z = pk[c*4+2]; u.w = pk[c*4+3];
      *(uint4*)(smem + LDS_SK + swz256(tok, p * 32 + c * 16)) = u;
    }
    uint32_t pk2[16];
    #pragma unroll
    for (int i = 0; i < 8; ++i){
      pk2[2*i]   = cvt_pk_bf16(bv[i].x, bv[i].y);
      pk2[2*i+1] = cvt_pk_bf16(bv[i].z, bv[i].w);
    }
    #pragma unroll
    for (int c = 0; c < 4; ++c){
      uint4 u; u.x = pk2[c*4]; u.y = pk2[c*4+1]; u.z = pk2[c*4+2]; u.w = pk2[c*4+3];
      *(uint4*)(smem + LDS_R3 + swz128(qrow, qq * 2 + c * 16)) = u;
    }
    const float4* s2 = (const float4*)(bx + qrow * BF + 64 + qq);
    #pragma unroll
    for (int i = 0; i < 4; ++i) ld[i] = s2[i];
  }
  __syncthreads();

  // KV GEMM
  f32x4 kv8[8];
  #pragma unroll
  for (int i = 0; i < 8; ++i) kv8[i] = vzero;
  if (w < 4){
    #pragma unroll
    for (int ks = 0; ks < 4; ++ks){
      bf16x8 a2[2];
      #pragma unroll
      for (int mf = 0; mf < 2; ++mf)
        a2[mf] = *(const bf16x8*)(wkvT + (w*32 + mf*16 + li) * 128 + ks*32 + g*8);
      #pragma unroll
      for (int n4 = 0; n4 < 4; ++n4){
        bf16x8 b4 = *(const bf16x8*)(smem + LDS_SK + swz256(n4*16 + li, (ks*32 + g*8) * 2));
        #pragma unroll
        for (int mf = 0; mf < 2; ++mf)
          kv8[mf*4+n4] = __builtin_amdgcn_mfma_f32_16x16x32_bf16(a2[mf], b4, kv8[mf*4+n4], 0, 0, 0);
      }
    }
  } else {
    #pragma unroll
    for (int ks = 0; ks < 4; ++ks){
      bf16x8 afr[4];
      #pragma unroll
      for (int m = 0; m < 4; ++m)
        afr[m] = *(const bf16x8*)(smem + LDS_SK + swz256(m*16 + li, (ks*32 + g*8) * 2));
      #pragma unroll
      for (int n2 = 0; n2 < 2; ++n2){
        int n = w * 32 + n2 * 16 + li;
        bf16x8 bfr = *(const bf16x8*)(wkvT + n * 128 + ks*32 + g*8);
        #pragma unroll
        for (int m = 0; m < 4; ++m)
          kv8[m*2+n2] = __builtin_amdgcn_mfma_f32_16x16x32_bf16(afr[m], bfr, kv8[m*2+n2], 0, 0, 0);
      }
    }
  }
  __syncthreads();

  if (w < 4){
    #pragma unroll
    for (int mf = 0; mf < 2; ++mf){
      int f0 = w*32 + mf*16 + g*4;
      f32x4 bb = *(const f32x4*)(bqkv + SF + f0);
      #pragma unroll
      for (int n4 = 0; n4 < 4; ++n4){
        f32x4 vv = kv8[mf*4+n4];
        uint2 u;
        u.x = cvt_pk_bf16(vv[0] + bb[0], vv[1] + bb[1]);
        u.y = cvt_pk_bf16(vv[2] + bb[2], vv[3] + bb[3]);
        *(uint2*)(smem + LDS_SK + swz256(n4*16 + li, f0 * 2)) = u;
      }
    }
  } else {
    #pragma unroll
    for (int n2 = 0; n2 < 2; ++n2){
      int feat = (w-4)*32 + n2*16 + li;
      float bias = bqkv[2*SF + feat];
      #pragma unroll
      for (int m = 0; m < 4; ++m){
        f32x4 vv = kv8[m*2+n2];
        uint2 u;
        u.x = cvt_pk_bf16(vv[0] + bias, vv[1] + bias);
        u.y = cvt_pk_bf16(vv[2] + bias, vv[3] + bias);
        *(uint2*)(smem + LDS_SVT + swz128(feat, (m*16 + g*4) * 2)) = u;
      }
    }
  }

  // Q^T GEMM
  f32x4 qacc[8];
  #pragma unroll
  for (int m = 0; m < 8; ++m) qacc[m] = vzero;
  for (int kc = 0; kc < 4; ++kc){
    __syncthreads();
    if (kc < 3){
      uint32_t pk[16];
      #pragma unroll
      for (int i = 0; i < 4; ++i){
        pk[2*i]   = cvt_pk_bf16(ld[i].x, ld[i].y);
        pk[2*i+1] = cvt_pk_bf16(ld[i].z, ld[i].w);
      }
      char* bufn = smem + LDS_R3 + ((kc + 1) & 1) * 16384;
      #pragma unroll
      for (int c = 0; c < 2; ++c){
        uint4 u; u.x = pk[c*4]; u.y = pk[c*4+1]; u.z = pk[c*4+2]; u.w = pk[c*4+3];
        *(uint4*)(bufn + swz128(qrow, qq * 2 + c * 16)) = u;
      }
      if (kc < 2){
        const float4* s_ = (const float4*)(bx + qrow * BF + (kc + 2) * 64 + qq);
        #pragma unroll
        for (int i = 0; i < 4; ++i) ld[i] = s_[i];
      }
    }
    const char* buf = smem + LDS_R3 + (kc & 1) * 16384;
    #pragma unroll
    for (int ks = 0; ks < 2; ++ks){
      bf16x8 a = *(const bf16x8*)(weffT + (w*16 + li) * 256 + kc*64 + ks*32 + g*8);
      #pragma unroll
      for (int nt = 0; nt < 8; ++nt){
        bf16x8 bq = *(const bf16x8*)(buf + swz128(nt*16 + li, (ks*32 + g*8) * 2));
        qacc[nt] = __builtin_amdgcn_mfma_f32_16x16x32_bf16(a, bq, qacc[nt], 0, 0, 0);
      }
    }
  }
  __syncthreads();

  {
    f32x4 be = *(const f32x4*)(beff + w*16 + g*4);
    #pragma unroll
    for (int nt = 0; nt < 8; ++nt){
      f32x4 vv = qacc[nt];
      uint2 u;
      u.x = cvt_pk_bf16(vv[0] + be[0], vv[1] + be[1]);
      u.y = cvt_pk_bf16(vv[2] + be[2], vv[3] + be[3]);
      *(uint2*)(smem + LDS_R3 + swz256(nt*16 + li, (w*16 + g*4) * 2)) = u;
    }
  }
  __syncthreads();

  f32x4 sacc[4][4];
  #pragma unroll
  for (int m = 0; m < 4; ++m)
    #pragma unroll
    for (int n = 0; n < 4; ++n) sacc[m][n] = vzero;
  {
    bf16x8 afr[4];
    #pragma unroll
    for (int m = 0; m < 4; ++m)
      afr[m] = *(const bf16x8*)(smem + LDS_SK + swz256(m*16 + li, (h*32 + g*8) * 2));
    #pragma unroll
    for (int n = 0; n < 4; ++n){
      bf16x8 bfr = *(const bf16x8*)(smem + LDS_R3 + swz256(qh*64 + n*16 + li, (h*32 + g*8) * 2));
      #pragma unroll
      for (int m = 0; m < 4; ++m)
        sacc[m][n] = __builtin_amdgcn_mfma_f32_16x16x32_bf16(afr[m], bfr, sacc[m][n], 0, 0, 0);
    }
  }
  __syncthreads();

  #pragma unroll
  for (int n = 0; n < 4; ++n){
    const float* bm = bmatT + ((size_t)(h * 256 + hf*128 + qh*64 + n*16 + li)) * 64;
    #pragma unroll
    for (int m = 0; m < 4; ++m)
      sacc[m][n] += *(const f32x4*)(bm + m*16 + g*4);
  }

  float sm[4];
  #pragma unroll
  for (int n = 0; n < 4; ++n){
    float mx = sacc[0][n][0];
    #pragma unroll
    for (int m = 0; m < 4; ++m)
      #pragma unroll
      for (int r = 0; r < 4; ++r) mx = fmaxf(mx, sacc[m][n][r]);
    mx = fmaxf(mx, __shfl_xor(mx, 16));
    mx = fmaxf(mx, __shfl_xor(mx, 32));
    float s0 = 0.f;
    #pragma unroll
    for (int m = 0; m < 4; ++m)
      #pragma unroll
      for (int r = 0; r < 4; ++r){
        float e = __builtin_amdgcn_exp2f(sacc[m][n][r] - mx);
        sacc[m][n][r] = e;
        s0 += e;
      }
    s0 += __shfl_xor(s0, 16);
    s0 += __shfl_xor(s0, 32);
    sm[n] = __builtin_amdgcn_rcpf(s0);
  }

  f32x4 oacc[2][2][2];
  #pragma unroll
  for (int hl = 0; hl < 2; ++hl)
    #pragma unroll
    for (int m2 = 0; m2 < 2; ++m2)
      #pragma unroll
      for (int n4 = 0; n4 < 2; ++n4) oacc[hl][m2][n4] = vzero;

  char* sp = smem + LDS_R3 + w * 4096;
  #pragma unroll
  for (int hl = 0; hl < 2; ++hl){
    #pragma unroll
    for (int n4 = 0; n4 < 2; ++n4){
      int n = hl * 2 + n4;
      #pragma unroll
      for (int m = 0; m < 4; ++m){
        uint2 u;
        u.x = cvt_pk_bf16(sacc[m][n][0], sacc[m][n][1]);
        u.y = cvt_pk_bf16(sacc[m][n][2], sacc[m][n][3]);
        *(uint2*)(sp + swz128(n4 * 16 + li, (m * 16 + g * 4) * 2)) = u;
      }
    }
    #pragma unroll
    for (int kk = 0; kk < 2; ++kk){
      bf16x8 afr2[2];
      #pragma unroll
      for (int m2 = 0; m2 < 2; ++m2)
        afr2[m2] = *(const bf16x8*)(smem + LDS_SVT + swz128(h*32 + m2*16 + li, (kk*32 + g*8) * 2));
      #pragma unroll
      for (int n4 = 0; n4 < 2; ++n4){
        bf16x8 bfr = *(const bf16x8*)(sp + swz128(n4 * 16 + li, (kk*32 + g*8) * 2));
        #pragma unroll
        for (int m2 = 0; m2 < 2; ++m2)
          oacc[hl][m2][n4] = __builtin_amdgcn_mfma_f32_16x16x32_bf16(afr2[m2], bfr, oacc[hl][m2][n4], 0, 0, 0);
      }
    }
  }
  __syncthreads();

  #pragma unroll
  for (int hl = 0; hl < 2; ++hl)
    #pragma unroll
    for (int m2 = 0; m2 < 2; ++m2)
      #pragma unroll
      for (int n4 = 0; n4 < 2; ++n4){
        float rs = sm[hl * 2 + n4];
        f32x4 vv = oacc[hl][m2][n4];
        uint2 u;
        u.x = cvt_pk_bf16(vv[0] * rs, vv[1] * rs);
        u.y = cvt_pk_bf16(vv[2] * rs, vv[3] * rs);
        int q = qh * 64 + hl * 32 + n4 * 16 + li;
        *(uint2*)(smem + LDS_R3 + swz256(q, (h*32 + m2*16 + g*4) * 2)) = u;
      }
  __syncthreads();

  f32x4 facc[2][8];
  #pragma unroll
  for (int mo = 0; mo < 2; ++mo)
    #pragma unroll
    for (int nt = 0; nt < 8; ++nt) facc[mo][nt] = vzero;

  #pragma unroll
  for (int kc = 0; kc < 4; ++kc){
    bf16x8 a2[2];
    #pragma unroll
    for (int mo = 0; mo < 2; ++mo)
      a2[mo] = *(const bf16x8*)(w2T + (w*32 + mo*16 + li) * 128 + kc*32 + g*8);
    #pragma unroll
    for (int nt = 0; nt < 8; ++nt){
      bf16x8 b8 = *(const bf16x8*)(smem + LDS_R3 + swz256(nt*16 + li, (kc*32 + g*8) * 2));
      #pragma unroll
      for (int mo = 0; mo < 2; ++mo)
        facc[mo][nt] = __builtin_amdgcn_mfma_f32_16x16x32_bf16(a2[mo], b8, facc[mo][nt], 0, 0, 0);
    }
  }

  float* op = out + (size_t)b * NB * BF + (size_t)hf * 128 * BF;
  #pragma unroll
  for (int mo = 0; mo < 2; ++mo){
    int c0 = w*32 + mo*16 + g*4;
    f32x4 bb = *(const f32x4*)(b2 + c0);
    #pragma unroll
    for (int nt = 0; nt < 8; ++nt){
      f32x4 vv = facc[mo][nt] + bb;
      *(f32x4*)(op + (size_t)(nt*16 + li) * BF + c0) = vv;
    }
  }
}

extern "C" void kernel_launch(void* const* d_in, const int* in_sizes, int n_in,
                              void* d_out, int out_size, void* d_ws, size_t ws_size,
                              hipStream_t stream)
{
  const float* big_x   = (const float*)d_in[0];
  const float* small_x = (const float*)d_in[1];
  const float* W1      = (const float*)d_in[2];
  const float* b1      = (const float*)d_in[3];
  const float* Wqkv    = (const float*)d_in[4];
  const float* bqkv    = (const float*)d_in[5];
  const float* W2      = (const float*)d_in[6];
  const float* b2      = (const float*)d_in[7];
  const float* tbl     = (const float*)d_in[8];
  float* out = (float*)d_out;

  (void)in_sizes; (void)n_in; (void)out_size;

  cowin_prep<<<417, 256, 0, stream>>>(W1, b1, Wqkv, bqkv, W2, tbl, d_ws);

  if (ws_size >= WS_NEED){
    cowin_kv<<<NBATCH, 256, 0, stream>>>(small_x, bqkv, d_ws);
    cowin_attn<<<NBATCH * 4, 256, 0, stream>>>(big_x, b2, d_ws, out);
  } else {
    hipFuncSetAttribute(reinterpret_cast<const void*>(cowin_main_fb),
                        hipFuncAttributeMaxDynamicSharedMemorySize, LDS_TOTAL);
    cowin_main_fb<<<NBATCH * 2, 512, LDS_TOTAL, stream>>>(big_x, small_x, bqkv, b2, d_ws, out);
  }
}